// Round 3
// baseline (339.402 us; speedup 1.0000x reference)
//
#include <hip/hip_runtime.h>
#include <hip/hip_bf16.h>

// Problem dims (fixed by reference): B=2,S=1024 -> T=2048 tokens
#define T_TOK 2048
#define DIM   2048   // D
#define FFN   1024   // F
#define NE    8      // experts
// top_k = 2 hardcoded

typedef __attribute__((ext_vector_type(8))) short bf16x8;
typedef __attribute__((ext_vector_type(8))) unsigned short u16x8;
typedef __attribute__((ext_vector_type(4))) float f32x4;

__device__ __forceinline__ unsigned short f2bf(float f) {
  __hip_bfloat16 h = __float2bfloat16(f);
  return __builtin_bit_cast(unsigned short, h);
}

__device__ __forceinline__ void gload_lds16(const unsigned short* g, unsigned short* l) {
  __builtin_amdgcn_global_load_lds(
      (const __attribute__((address_space(1))) void*)g,
      (__attribute__((address_space(3))) void*)l, 16, 0, 0);
}

// ---------------- fp32 -> bf16 conversion (x only) ----------------
__global__ void cvt_f32_to_bf16(const float* __restrict__ in,
                                unsigned short* __restrict__ out, int n4) {
  int i = blockIdx.x * blockDim.x + threadIdx.x;
  int stride = gridDim.x * blockDim.x;
  for (; i < n4; i += stride) {
    float4 v = reinterpret_cast<const float4*>(in)[i];
    ushort4 o;
    o.x = f2bf(v.x); o.y = f2bf(v.y); o.z = f2bf(v.z); o.w = f2bf(v.w);
    reinterpret_cast<ushort4*>(out)[i] = o;
  }
}

// ---------------- router: logits + top2 + softmax gates ----------------
__global__ __launch_bounds__(256) void router_topk(
    const float* __restrict__ x, const float* __restrict__ wr,
    int* __restrict__ top_i, float* __restrict__ top_g) {
  int t = blockIdx.x * 4 + (threadIdx.x >> 6);
  int lane = threadIdx.x & 63;
  const float4* xr = reinterpret_cast<const float4*>(x) + (size_t)t * (DIM / 4);
  const float4* wrv = reinterpret_cast<const float4*>(wr);
  float acc[NE];
#pragma unroll
  for (int e = 0; e < NE; ++e) acc[e] = 0.f;
#pragma unroll
  for (int it = 0; it < DIM / 4 / 64; ++it) {
    int d4 = it * 64 + lane;
    float4 xv = xr[d4];
#pragma unroll
    for (int e = 0; e < NE; ++e) {
      float4 wv = wrv[e * (DIM / 4) + d4];
      acc[e] += xv.x * wv.x + xv.y * wv.y + xv.z * wv.z + xv.w * wv.w;
    }
  }
#pragma unroll
  for (int off = 32; off > 0; off >>= 1) {
#pragma unroll
    for (int e = 0; e < NE; ++e) acc[e] += __shfl_xor(acc[e], off, 64);
  }
  if (lane == 0) {
    int i0 = 0; float m0 = acc[0];
#pragma unroll
    for (int e = 1; e < NE; ++e) if (acc[e] > m0) { m0 = acc[e]; i0 = e; }
    int i1 = -1; float m1 = -3.4e38f;
#pragma unroll
    for (int e = 0; e < NE; ++e) if (e != i0 && acc[e] > m1) { m1 = acc[e]; i1 = e; }
    float tv = expf(m1 - m0);
    float den = 1.f + tv;
    top_i[t * 2 + 0] = i0; top_i[t * 2 + 1] = i1;
    top_g[t * 2 + 0] = 1.f / den; top_g[t * 2 + 1] = tv / den;
  }
}

// ---------------- count per expert + exclusive prefix offsets ----------------
__global__ void count_offsets(const int* __restrict__ top_i,
                              int* __restrict__ offs, int* __restrict__ cursor) {
  __shared__ int cnt[NE];
  if (threadIdx.x < NE) cnt[threadIdx.x] = 0;
  __syncthreads();
  for (int i = threadIdx.x; i < T_TOK * 2; i += blockDim.x) atomicAdd(&cnt[top_i[i]], 1);
  __syncthreads();
  if (threadIdx.x == 0) {
    int s = 0;
    for (int e = 0; e < NE; ++e) { offs[e] = s; cursor[e] = s; s += cnt[e]; }
    offs[NE] = s;
  }
}

// ---------------- scatter tokens into compact per-expert lists ----------------
__global__ void scatter_tokens(const int* __restrict__ top_i, const float* __restrict__ top_g,
                               int* __restrict__ cursor, int* __restrict__ tok_list,
                               float* __restrict__ gate_lst, int* __restrict__ slot_lst) {
  int t = blockIdx.x * blockDim.x + threadIdx.x;
  if (t >= T_TOK) return;
#pragma unroll
  for (int s = 0; s < 2; ++s) {
    int e = top_i[t * 2 + s];
    int p = atomicAdd(&cursor[e], 1);
    tok_list[p] = t;
    gate_lst[p] = top_g[t * 2 + s];
    slot_lst[p] = s;
  }
}

// ============ fused gate+up grouped GEMM: BM=64, BN=128(pair), BK=64 ============
// Double-buffered LDS (T3-min pipeline). A: bf16 x via global_load_lds with
// pre-swizzled source. B: fp32 weights reg-staged (load early / cvt+ds_write late),
// swizzled write chunk c^=(row&7). Read offset (kk*4+(lane>>4))^(lane&7).
__global__ __launch_bounds__(256, 2) void gateup_gemm(
    const unsigned short* __restrict__ xb, const float* __restrict__ wg,
    const float* __restrict__ wu, const int* __restrict__ tok_list,
    const int* __restrict__ offs, unsigned short* __restrict__ hbuf) {
  const int e = blockIdx.z;
  const int row0 = offs[e];
  const int n_e = offs[e + 1] - row0;
  const int mt = blockIdx.y;
  if (mt * 64 >= n_e) return;
  const int nt = blockIdx.x;

  __shared__ unsigned short As[2][64 * 64];    // 2 x 8KB
  __shared__ unsigned short Bg[2][128 * 64];   // 2 x 16KB
  __shared__ unsigned short Bu[2][128 * 64];   // 2 x 16KB

  const int tid = threadIdx.x;
  const int wid = tid >> 6;
  const int lane = tid & 63;

  // ---- A staging (gload_lds, source pre-swizzled) ----
  const int gchunk = (((lane & 7) ^ ((lane >> 3) & 7)) << 3);
  const unsigned short* gA[2];
  int lAoff[2];
#pragma unroll
  for (int p = 0; p < 2; ++p) {
    int rt = wid * 16 + p * 8 + (lane >> 3);
    int ar = mt * 64 + rt; if (ar >= n_e) ar = n_e - 1;
    gA[p] = xb + (size_t)tok_list[row0 + ar] * DIM + gchunk;
    lAoff[p] = (wid * 16 + p * 8) * 64;
  }

  // ---- B staging (fp32 reg-staged): wave rows wid*32 + p*8 + (lane>>3) ----
  const float* gGb = wg + ((size_t)e * FFN + nt * 128 + wid * 32 + (lane >> 3)) * DIM + (lane & 7) * 8;
  const float* gUb = wu + ((size_t)e * FFN + nt * 128 + wid * 32 + (lane >> 3)) * DIM + (lane & 7) * 8;
  // LDS write element offset: row lrow+p*8, chunk (lane&7)^(lane>>3)
  const int lrow = wid * 32 + (lane >> 3);
  const int wboff = lrow * 64 + ((lane & 7) ^ (lane >> 3)) * 8;

  float Rg[4][8], Ru[4][8];

  auto issueA = [&](int k0, int buf) {
#pragma unroll
    for (int p = 0; p < 2; ++p) gload_lds16(gA[p] + k0, &As[buf][lAoff[p]]);
  };
  auto issueB = [&](int k0) {
#pragma unroll
    for (int p = 0; p < 4; ++p) {
      const float4* pg = reinterpret_cast<const float4*>(gGb + (size_t)p * 8 * DIM + k0);
      const float4* pu = reinterpret_cast<const float4*>(gUb + (size_t)p * 8 * DIM + k0);
      *reinterpret_cast<float4*>(&Rg[p][0]) = pg[0];
      *reinterpret_cast<float4*>(&Rg[p][4]) = pg[1];
      *reinterpret_cast<float4*>(&Ru[p][0]) = pu[0];
      *reinterpret_cast<float4*>(&Ru[p][4]) = pu[1];
    }
  };
  auto cvtWriteB = [&](int buf) {
#pragma unroll
    for (int p = 0; p < 4; ++p) {
      u16x8 vg, vu;
#pragma unroll
      for (int q = 0; q < 8; ++q) { vg[q] = f2bf(Rg[p][q]); vu[q] = f2bf(Ru[p][q]); }
      *reinterpret_cast<u16x8*>(&Bg[buf][wboff + p * 512]) = vg;
      *reinterpret_cast<u16x8*>(&Bu[buf][wboff + p * 512]) = vu;
    }
  };

  f32x4 accg[2][4];
  f32x4 accu[2][4];
#pragma unroll
  for (int i = 0; i < 2; ++i)
#pragma unroll
    for (int j = 0; j < 4; ++j) {
      accg[i][j] = (f32x4){0.f, 0.f, 0.f, 0.f};
      accu[i][j] = (f32x4){0.f, 0.f, 0.f, 0.f};
    }

  const int warow = (wid >> 1) * 32;
  const int wacol = (wid & 1) * 64;
  const int frow = lane & 15;
  const int eo0 = ((((lane >> 4)) ^ (lane & 7)) << 3);
  const int eo1 = (((4 + (lane >> 4)) ^ (lane & 7)) << 3);

  // prologue: fill buffer 0
  issueA(0, 0);
  issueB(0);
  cvtWriteB(0);
  __syncthreads();

  const int NT = DIM / 64;
  int cur = 0;
  for (int t = 0; t < NT; ++t) {
    if (t + 1 < NT) { issueA((t + 1) * 64, cur ^ 1); issueB((t + 1) * 64); }
#pragma unroll
    for (int kk = 0; kk < 2; ++kk) {
      const int eo = kk ? eo1 : eo0;
      bf16x8 af[2], bg[4], bu[4];
#pragma unroll
      for (int i = 0; i < 2; ++i)
        af[i] = *reinterpret_cast<const bf16x8*>(&As[cur][(warow + i * 16 + frow) * 64 + eo]);
#pragma unroll
      for (int j = 0; j < 4; ++j) {
        bg[j] = *reinterpret_cast<const bf16x8*>(&Bg[cur][(wacol + j * 16 + frow) * 64 + eo]);
        bu[j] = *reinterpret_cast<const bf16x8*>(&Bu[cur][(wacol + j * 16 + frow) * 64 + eo]);
      }
#pragma unroll
      for (int i = 0; i < 2; ++i)
#pragma unroll
        for (int j = 0; j < 4; ++j) {
          accg[i][j] = __builtin_amdgcn_mfma_f32_16x16x32_bf16(af[i], bg[j], accg[i][j], 0, 0, 0);
          accu[i][j] = __builtin_amdgcn_mfma_f32_16x16x32_bf16(af[i], bu[j], accu[i][j], 0, 0, 0);
        }
    }
    if (t + 1 < NT) cvtWriteB(cur ^ 1);
    __syncthreads();
    cur ^= 1;
  }

  // epilogue: h = silu(g)*u -> bf16
#pragma unroll
  for (int i = 0; i < 2; ++i) {
#pragma unroll
    for (int jj = 0; jj < 4; ++jj) {
      int r = mt * 64 + warow + i * 16 + (lane >> 4) * 4 + jj;
      if (r < n_e) {
#pragma unroll
        for (int j = 0; j < 4; ++j) {
          float g = accg[i][j][jj];
          float u = accu[i][j][jj];
          float h = (g / (1.f + __expf(-g))) * u;
          int f = nt * 128 + wacol + j * 16 + (lane & 15);
          hbuf[(size_t)(row0 + r) * FFN + f] = f2bf(h);
        }
      }
    }
  }
}

// ============ grouped down GEMM: BM=64, BN=128, BK=64, dbuf pipeline ============
__global__ __launch_bounds__(256, 3) void down_gemm(
    const unsigned short* __restrict__ hbuf, const float* __restrict__ wd,
    const int* __restrict__ tok_list, const float* __restrict__ gate_lst,
    const int* __restrict__ slot_lst, const int* __restrict__ offs,
    float* __restrict__ yslots) {
  const int e = blockIdx.z;
  const int row0 = offs[e];
  const int n_e = offs[e + 1] - row0;
  const int mt = blockIdx.y;
  if (mt * 64 >= n_e) return;
  const int nt = blockIdx.x;  // D tile

  __shared__ unsigned short As[2][64 * 64];    // 2 x 8KB
  __shared__ unsigned short Bs[2][128 * 64];   // 2 x 16KB

  const int tid = threadIdx.x;
  const int wid = tid >> 6;
  const int lane = tid & 63;

  const int gchunk = (((lane & 7) ^ ((lane >> 3) & 7)) << 3);
  const unsigned short* gA[2];
  int lAoff[2];
#pragma unroll
  for (int p = 0; p < 2; ++p) {
    int rt = wid * 16 + p * 8 + (lane >> 3);
    int ar = mt * 64 + rt; if (ar >= n_e) ar = n_e - 1;
    gA[p] = hbuf + (size_t)(row0 + ar) * FFN + gchunk;
    lAoff[p] = (wid * 16 + p * 8) * 64;
  }

  const float* gBb = wd + ((size_t)e * DIM + nt * 128 + wid * 32 + (lane >> 3)) * FFN + (lane & 7) * 8;
  const int lrow = wid * 32 + (lane >> 3);
  const int wboff = lrow * 64 + ((lane & 7) ^ (lane >> 3)) * 8;

  float Rb[4][8];

  auto issueA = [&](int k0, int buf) {
#pragma unroll
    for (int p = 0; p < 2; ++p) gload_lds16(gA[p] + k0, &As[buf][lAoff[p]]);
  };
  auto issueB = [&](int k0) {
#pragma unroll
    for (int p = 0; p < 4; ++p) {
      const float4* pb = reinterpret_cast<const float4*>(gBb + (size_t)p * 8 * FFN + k0);
      *reinterpret_cast<float4*>(&Rb[p][0]) = pb[0];
      *reinterpret_cast<float4*>(&Rb[p][4]) = pb[1];
    }
  };
  auto cvtWriteB = [&](int buf) {
#pragma unroll
    for (int p = 0; p < 4; ++p) {
      u16x8 vb;
#pragma unroll
      for (int q = 0; q < 8; ++q) vb[q] = f2bf(Rb[p][q]);
      *reinterpret_cast<u16x8*>(&Bs[buf][wboff + p * 512]) = vb;
    }
  };

  f32x4 acc[2][4];
#pragma unroll
  for (int i = 0; i < 2; ++i)
#pragma unroll
    for (int j = 0; j < 4; ++j) acc[i][j] = (f32x4){0.f, 0.f, 0.f, 0.f};

  const int warow = (wid >> 1) * 32;
  const int wacol = (wid & 1) * 64;
  const int frow = lane & 15;
  const int eo0 = ((((lane >> 4)) ^ (lane & 7)) << 3);
  const int eo1 = (((4 + (lane >> 4)) ^ (lane & 7)) << 3);

  issueA(0, 0);
  issueB(0);
  cvtWriteB(0);
  __syncthreads();

  const int NT = FFN / 64;
  int cur = 0;
  for (int t = 0; t < NT; ++t) {
    if (t + 1 < NT) { issueA((t + 1) * 64, cur ^ 1); issueB((t + 1) * 64); }
#pragma unroll
    for (int kk = 0; kk < 2; ++kk) {
      const int eo = kk ? eo1 : eo0;
      bf16x8 af[2], bf[4];
#pragma unroll
      for (int i = 0; i < 2; ++i)
        af[i] = *reinterpret_cast<const bf16x8*>(&As[cur][(warow + i * 16 + frow) * 64 + eo]);
#pragma unroll
      for (int j = 0; j < 4; ++j)
        bf[j] = *reinterpret_cast<const bf16x8*>(&Bs[cur][(wacol + j * 16 + frow) * 64 + eo]);
#pragma unroll
      for (int i = 0; i < 2; ++i)
#pragma unroll
        for (int j = 0; j < 4; ++j)
          acc[i][j] = __builtin_amdgcn_mfma_f32_16x16x32_bf16(af[i], bf[j], acc[i][j], 0, 0, 0);
    }
    if (t + 1 < NT) cvtWriteB(cur ^ 1);
    __syncthreads();
    cur ^= 1;
  }

#pragma unroll
  for (int i = 0; i < 2; ++i) {
#pragma unroll
    for (int jj = 0; jj < 4; ++jj) {
      int r = mt * 64 + warow + i * 16 + (lane >> 4) * 4 + jj;
      if (r < n_e) {
        int tk = tok_list[row0 + r];
        float gt = gate_lst[row0 + r];
        int sl = slot_lst[row0 + r];
        float* yrow = yslots + ((size_t)sl * T_TOK + tk) * DIM;
#pragma unroll
        for (int j = 0; j < 4; ++j) {
          int d = nt * 128 + wacol + j * 16 + (lane & 15);
          yrow[d] = gt * acc[i][j][jj];
        }
      }
    }
  }
}

// ---------------- combine slots ----------------
__global__ void combine(const float* __restrict__ y, float* __restrict__ out) {
  int i = blockIdx.x * blockDim.x + threadIdx.x;
  int stride = gridDim.x * blockDim.x;
  const float4* y0 = reinterpret_cast<const float4*>(y);
  const float4* y1 = reinterpret_cast<const float4*>(y + (size_t)T_TOK * DIM);
  float4* o = reinterpret_cast<float4*>(out);
  for (; i < T_TOK * DIM / 4; i += stride) {
    float4 a = y0[i], b = y1[i];
    float4 r;
    r.x = a.x + b.x; r.y = a.y + b.y; r.z = a.z + b.z; r.w = a.w + b.w;
    o[i] = r;
  }
}

extern "C" void kernel_launch(void* const* d_in, const int* in_sizes, int n_in,
                              void* d_out, int out_size, void* d_ws, size_t ws_size,
                              hipStream_t stream) {
  const float* x = (const float*)d_in[0];
  const float* wr = (const float*)d_in[1];
  const float* wg = (const float*)d_in[2];
  const float* wu = (const float*)d_in[3];
  const float* wd = (const float*)d_in[4];
  float* out = (float*)d_out;

  char* ws = (char*)d_ws;
  size_t off = 0;
  auto alloc = [&](size_t bytes) {
    char* p = ws + off;
    off += (bytes + 255) & ~(size_t)255;
    return p;
  };
  unsigned short* xb   = (unsigned short*)alloc((size_t)T_TOK * DIM * 2);
  unsigned short* hbuf = (unsigned short*)alloc((size_t)T_TOK * 2 * FFN * 2);
  float* yslots        = (float*)alloc((size_t)2 * T_TOK * DIM * 4);
  int* top_i     = (int*)alloc(T_TOK * 2 * 4);
  float* top_g   = (float*)alloc(T_TOK * 2 * 4);
  int* tok_list  = (int*)alloc(T_TOK * 2 * 4);
  float* gate_lst = (float*)alloc(T_TOK * 2 * 4);
  int* slot_lst  = (int*)alloc(T_TOK * 2 * 4);
  int* offs      = (int*)alloc(64);
  int* cursor    = (int*)alloc(64);
  if (off > ws_size) return;

  cvt_f32_to_bf16<<<2048, 256, 0, stream>>>(x, xb, T_TOK * DIM / 4);
  router_topk<<<T_TOK / 4, 256, 0, stream>>>(x, wr, top_i, top_g);
  count_offsets<<<1, 256, 0, stream>>>(top_i, offs, cursor);
  scatter_tokens<<<(T_TOK + 255) / 256, 256, 0, stream>>>(top_i, top_g, cursor, tok_list,
                                                          gate_lst, slot_lst);
  gateup_gemm<<<dim3(FFN / 128, 32, NE), 256, 0, stream>>>(xb, wg, wu, tok_list, offs, hbuf);
  down_gemm<<<dim3(DIM / 128, 32, NE), 256, 0, stream>>>(hbuf, wd, tok_list, gate_lst,
                                                         slot_lst, offs, yslots);
  combine<<<2048, 256, 0, stream>>>(yslots, out);
}

// Round 4
// 261.894 us; speedup vs baseline: 1.2959x; 1.2959x over previous
//
#include <hip/hip_runtime.h>
#include <hip/hip_bf16.h>

// Problem dims (fixed by reference): B=2,S=1024 -> T=2048 tokens
#define T_TOK 2048
#define DIM   2048   // D
#define FFN   1024   // F
#define NE    8      // experts
// top_k = 2 hardcoded

typedef __attribute__((ext_vector_type(8))) short bf16x8;
typedef __attribute__((ext_vector_type(4))) float f32x4;

__device__ __forceinline__ unsigned short f2bf(float f) {
  __hip_bfloat16 h = __float2bfloat16(f);
  return __builtin_bit_cast(unsigned short, h);
}

__device__ __forceinline__ void gload_lds16(const unsigned short* g, unsigned short* l) {
  __builtin_amdgcn_global_load_lds(
      (const __attribute__((address_space(1))) void*)g,
      (__attribute__((address_space(3))) void*)l, 16, 0, 0);
}

// ---------------- zero d_out ----------------
__global__ void zero_out(float4* __restrict__ o, int n4) {
  int i = blockIdx.x * blockDim.x + threadIdx.x;
  int stride = gridDim.x * blockDim.x;
  float4 z = {0.f, 0.f, 0.f, 0.f};
  for (; i < n4; i += stride) o[i] = z;
}

// ---------------- fp32 -> bf16 conversion: x + 3 weight tensors ----------------
#define XN4 (T_TOK * DIM / 4)            // 2^20
#define WN4 (NE * FFN * DIM / 4)         // 2^22
__global__ void cvt_all(const float* __restrict__ x, const float* __restrict__ wg,
                        const float* __restrict__ wu, const float* __restrict__ wd,
                        unsigned short* __restrict__ xb, unsigned short* __restrict__ wgb,
                        unsigned short* __restrict__ wub, unsigned short* __restrict__ wdb) {
  long i = (long)blockIdx.x * blockDim.x + threadIdx.x;
  long stride = (long)gridDim.x * blockDim.x;
  const long TOTAL = (long)XN4 + 3L * WN4;
  for (; i < TOTAL; i += stride) {
    const float4* src; ushort4* dst; long j;
    if (i < XN4) {
      src = reinterpret_cast<const float4*>(x); dst = reinterpret_cast<ushort4*>(xb); j = i;
    } else {
      long k = i - XN4; int seg = (int)(k >> 22); j = k & (WN4 - 1);
      src = reinterpret_cast<const float4*>(seg == 0 ? wg : (seg == 1 ? wu : wd));
      dst = reinterpret_cast<ushort4*>(seg == 0 ? wgb : (seg == 1 ? wub : wdb));
    }
    float4 v = src[j];
    ushort4 o;
    o.x = f2bf(v.x); o.y = f2bf(v.y); o.z = f2bf(v.z); o.w = f2bf(v.w);
    dst[j] = o;
  }
}

// ---------------- router: logits + top2 + softmax gates ----------------
__global__ __launch_bounds__(256) void router_topk(
    const float* __restrict__ x, const float* __restrict__ wr,
    int* __restrict__ top_i, float* __restrict__ top_g) {
  int t = blockIdx.x * 4 + (threadIdx.x >> 6);
  int lane = threadIdx.x & 63;
  const float4* xr = reinterpret_cast<const float4*>(x) + (size_t)t * (DIM / 4);
  const float4* wrv = reinterpret_cast<const float4*>(wr);
  float acc[NE];
#pragma unroll
  for (int e = 0; e < NE; ++e) acc[e] = 0.f;
#pragma unroll
  for (int it = 0; it < DIM / 4 / 64; ++it) {
    int d4 = it * 64 + lane;
    float4 xv = xr[d4];
#pragma unroll
    for (int e = 0; e < NE; ++e) {
      float4 wv = wrv[e * (DIM / 4) + d4];
      acc[e] += xv.x * wv.x + xv.y * wv.y + xv.z * wv.z + xv.w * wv.w;
    }
  }
#pragma unroll
  for (int off = 32; off > 0; off >>= 1) {
#pragma unroll
    for (int e = 0; e < NE; ++e) acc[e] += __shfl_xor(acc[e], off, 64);
  }
  if (lane == 0) {
    int i0 = 0; float m0 = acc[0];
#pragma unroll
    for (int e = 1; e < NE; ++e) if (acc[e] > m0) { m0 = acc[e]; i0 = e; }
    int i1 = -1; float m1 = -3.4e38f;
#pragma unroll
    for (int e = 0; e < NE; ++e) if (e != i0 && acc[e] > m1) { m1 = acc[e]; i1 = e; }
    float tv = expf(m1 - m0);
    float den = 1.f + tv;
    top_i[t * 2 + 0] = i0; top_i[t * 2 + 1] = i1;
    top_g[t * 2 + 0] = 1.f / den; top_g[t * 2 + 1] = tv / den;
  }
}

// ---------------- count per expert + exclusive prefix offsets ----------------
__global__ void count_offsets(const int* __restrict__ top_i,
                              int* __restrict__ offs, int* __restrict__ cursor) {
  __shared__ int cnt[NE];
  if (threadIdx.x < NE) cnt[threadIdx.x] = 0;
  __syncthreads();
  for (int i = threadIdx.x; i < T_TOK * 2; i += blockDim.x) atomicAdd(&cnt[top_i[i]], 1);
  __syncthreads();
  if (threadIdx.x == 0) {
    int s = 0;
    for (int e = 0; e < NE; ++e) { offs[e] = s; cursor[e] = s; s += cnt[e]; }
    offs[NE] = s;
  }
}

// ---------------- scatter tokens into compact per-expert lists ----------------
__global__ void scatter_tokens(const int* __restrict__ top_i, const float* __restrict__ top_g,
                               int* __restrict__ cursor, int* __restrict__ tok_list,
                               float* __restrict__ gate_lst) {
  int t = blockIdx.x * blockDim.x + threadIdx.x;
  if (t >= T_TOK) return;
#pragma unroll
  for (int s = 0; s < 2; ++s) {
    int e = top_i[t * 2 + s];
    int p = atomicAdd(&cursor[e], 1);
    tok_list[p] = t;
    gate_lst[p] = top_g[t * 2 + s];
  }
}

// ============ fused gate+up grouped GEMM: BM=64, BN=128, BK=64, dbuf 2-phase ============
// All staging via global_load_lds (bf16), pre-swizzled source chunk c^=(row&7).
// Flat grid, e = bid&7 (expert->XCD affinity, m09), mt fastest (co-resident blocks
// share B tiles in the XCD's L2). Read offset (kk*4+(lane>>4))^(lane&7).
__global__ __launch_bounds__(256, 2) void gateup_gemm(
    const unsigned short* __restrict__ xb, const unsigned short* __restrict__ wgb,
    const unsigned short* __restrict__ wub, const int* __restrict__ tok_list,
    const int* __restrict__ offs, unsigned short* __restrict__ hbuf) {
  const int bid = blockIdx.x;
  const int e = bid & 7;
  const int rem = bid >> 3;
  const int nt = rem >> 5;        // 8 N-tiles (FFN/128)
  const int mt = rem & 31;        // 32 M-tiles max
  const int row0 = offs[e];
  const int n_e = offs[e + 1] - row0;
  if (mt * 64 >= n_e) return;

  __shared__ unsigned short As[2][64 * 64];    // 2 x 8KB
  __shared__ unsigned short Bg[2][128 * 64];   // 2 x 16KB
  __shared__ unsigned short Bu[2][128 * 64];   // 2 x 16KB

  const int tid = threadIdx.x;
  const int wid = tid >> 6;
  const int lane = tid & 63;

  const int gchunk = (((lane & 7) ^ ((lane >> 3) & 7)) << 3);

  const unsigned short* gA[2];
  int lAoff[2];
#pragma unroll
  for (int p = 0; p < 2; ++p) {
    int rt = wid * 16 + p * 8 + (lane >> 3);
    int ar = mt * 64 + rt; if (ar >= n_e) ar = n_e - 1;
    gA[p] = xb + (size_t)tok_list[row0 + ar] * DIM + gchunk;
    lAoff[p] = (wid * 16 + p * 8) * 64;
  }
  const size_t wbase = (size_t)e * FFN * DIM + (size_t)(nt * 128) * DIM;
  const unsigned short* gG[4];
  const unsigned short* gU[4];
  int lBoff[4];
#pragma unroll
  for (int p = 0; p < 4; ++p) {
    int rt = wid * 32 + p * 8 + (lane >> 3);
    gG[p] = wgb + wbase + (size_t)rt * DIM + gchunk;
    gU[p] = wub + wbase + (size_t)rt * DIM + gchunk;
    lBoff[p] = (wid * 32 + p * 8) * 64;
  }

  auto stage = [&](int buf, int k0) {
#pragma unroll
    for (int p = 0; p < 2; ++p) gload_lds16(gA[p] + k0, &As[buf][lAoff[p]]);
#pragma unroll
    for (int p = 0; p < 4; ++p) {
      gload_lds16(gG[p] + k0, &Bg[buf][lBoff[p]]);
      gload_lds16(gU[p] + k0, &Bu[buf][lBoff[p]]);
    }
  };

  f32x4 accg[2][4];
  f32x4 accu[2][4];
#pragma unroll
  for (int i = 0; i < 2; ++i)
#pragma unroll
    for (int j = 0; j < 4; ++j) {
      accg[i][j] = (f32x4){0.f, 0.f, 0.f, 0.f};
      accu[i][j] = (f32x4){0.f, 0.f, 0.f, 0.f};
    }

  const int warow = (wid >> 1) * 32;
  const int wacol = (wid & 1) * 64;
  const int frow = lane & 15;
  const int eo0 = ((((lane >> 4)) ^ (lane & 7)) << 3);
  const int eo1 = (((4 + (lane >> 4)) ^ (lane & 7)) << 3);

  stage(0, 0);
  __syncthreads();

  const int NT = DIM / 64;
  int cur = 0;
  for (int t = 0; t < NT; ++t) {
    if (t + 1 < NT) stage(cur ^ 1, (t + 1) * 64);
#pragma unroll
    for (int kk = 0; kk < 2; ++kk) {
      const int eo = kk ? eo1 : eo0;
      bf16x8 af[2], bg[4], bu[4];
#pragma unroll
      for (int i = 0; i < 2; ++i)
        af[i] = *reinterpret_cast<const bf16x8*>(&As[cur][(warow + i * 16 + frow) * 64 + eo]);
#pragma unroll
      for (int j = 0; j < 4; ++j) {
        bg[j] = *reinterpret_cast<const bf16x8*>(&Bg[cur][(wacol + j * 16 + frow) * 64 + eo]);
        bu[j] = *reinterpret_cast<const bf16x8*>(&Bu[cur][(wacol + j * 16 + frow) * 64 + eo]);
      }
#pragma unroll
      for (int i = 0; i < 2; ++i)
#pragma unroll
        for (int j = 0; j < 4; ++j) {
          accg[i][j] = __builtin_amdgcn_mfma_f32_16x16x32_bf16(af[i], bg[j], accg[i][j], 0, 0, 0);
          accu[i][j] = __builtin_amdgcn_mfma_f32_16x16x32_bf16(af[i], bu[j], accu[i][j], 0, 0, 0);
        }
    }
    __syncthreads();
    cur ^= 1;
  }

  // epilogue: h = silu(g)*u -> bf16
#pragma unroll
  for (int i = 0; i < 2; ++i) {
#pragma unroll
    for (int jj = 0; jj < 4; ++jj) {
      int r = mt * 64 + warow + i * 16 + (lane >> 4) * 4 + jj;
      if (r < n_e) {
#pragma unroll
        for (int j = 0; j < 4; ++j) {
          float g = accg[i][j][jj];
          float u = accu[i][j][jj];
          float h = (g / (1.f + __expf(-g))) * u;
          int f = nt * 128 + wacol + j * 16 + (lane & 15);
          hbuf[(size_t)(row0 + r) * FFN + f] = f2bf(h);
        }
      }
    }
  }
}

// ============ grouped down GEMM: BM=64, BN=128, BK=64, dbuf 2-phase ============
// Epilogue: atomicAdd into out (exactly 2 fp32 contributions/element -> deterministic).
__global__ __launch_bounds__(256, 3) void down_gemm(
    const unsigned short* __restrict__ hbuf, const unsigned short* __restrict__ wdb,
    const int* __restrict__ tok_list, const float* __restrict__ gate_lst,
    const int* __restrict__ offs, float* __restrict__ out) {
  const int bid = blockIdx.x;
  const int e = bid & 7;
  const int rem = bid >> 3;
  const int nt = rem >> 5;        // 16 N-tiles (DIM/128)
  const int mt = rem & 31;
  const int row0 = offs[e];
  const int n_e = offs[e + 1] - row0;
  if (mt * 64 >= n_e) return;

  __shared__ unsigned short As[2][64 * 64];    // 2 x 8KB
  __shared__ unsigned short Bs[2][128 * 64];   // 2 x 16KB

  const int tid = threadIdx.x;
  const int wid = tid >> 6;
  const int lane = tid & 63;

  const int gchunk = (((lane & 7) ^ ((lane >> 3) & 7)) << 3);

  const unsigned short* gA[2];
  int lAoff[2];
#pragma unroll
  for (int p = 0; p < 2; ++p) {
    int rt = wid * 16 + p * 8 + (lane >> 3);
    int ar = mt * 64 + rt; if (ar >= n_e) ar = n_e - 1;
    gA[p] = hbuf + (size_t)(row0 + ar) * FFN + gchunk;
    lAoff[p] = (wid * 16 + p * 8) * 64;
  }
  const unsigned short* gB[4];
  int lBoff[4];
#pragma unroll
  for (int p = 0; p < 4; ++p) {
    int rt = wid * 32 + p * 8 + (lane >> 3);
    gB[p] = wdb + ((size_t)e * DIM + nt * 128 + rt) * FFN + gchunk;
    lBoff[p] = (wid * 32 + p * 8) * 64;
  }

  auto stage = [&](int buf, int k0) {
#pragma unroll
    for (int p = 0; p < 2; ++p) gload_lds16(gA[p] + k0, &As[buf][lAoff[p]]);
#pragma unroll
    for (int p = 0; p < 4; ++p) gload_lds16(gB[p] + k0, &Bs[buf][lBoff[p]]);
  };

  f32x4 acc[2][4];
#pragma unroll
  for (int i = 0; i < 2; ++i)
#pragma unroll
    for (int j = 0; j < 4; ++j) acc[i][j] = (f32x4){0.f, 0.f, 0.f, 0.f};

  const int warow = (wid >> 1) * 32;
  const int wacol = (wid & 1) * 64;
  const int frow = lane & 15;
  const int eo0 = ((((lane >> 4)) ^ (lane & 7)) << 3);
  const int eo1 = (((4 + (lane >> 4)) ^ (lane & 7)) << 3);

  stage(0, 0);
  __syncthreads();

  const int NT = FFN / 64;
  int cur = 0;
  for (int t = 0; t < NT; ++t) {
    if (t + 1 < NT) stage(cur ^ 1, (t + 1) * 64);
#pragma unroll
    for (int kk = 0; kk < 2; ++kk) {
      const int eo = kk ? eo1 : eo0;
      bf16x8 af[2], bf[4];
#pragma unroll
      for (int i = 0; i < 2; ++i)
        af[i] = *reinterpret_cast<const bf16x8*>(&As[cur][(warow + i * 16 + frow) * 64 + eo]);
#pragma unroll
      for (int j = 0; j < 4; ++j)
        bf[j] = *reinterpret_cast<const bf16x8*>(&Bs[cur][(wacol + j * 16 + frow) * 64 + eo]);
#pragma unroll
      for (int i = 0; i < 2; ++i)
#pragma unroll
        for (int j = 0; j < 4; ++j)
          acc[i][j] = __builtin_amdgcn_mfma_f32_16x16x32_bf16(af[i], bf[j], acc[i][j], 0, 0, 0);
    }
    __syncthreads();
    cur ^= 1;
  }

#pragma unroll
  for (int i = 0; i < 2; ++i) {
#pragma unroll
    for (int jj = 0; jj < 4; ++jj) {
      int r = mt * 64 + warow + i * 16 + (lane >> 4) * 4 + jj;
      if (r < n_e) {
        int tk = tok_list[row0 + r];
        float gt = gate_lst[row0 + r];
        float* yrow = out + (size_t)tk * DIM;
#pragma unroll
        for (int j = 0; j < 4; ++j) {
          int d = nt * 128 + wacol + j * 16 + (lane & 15);
          atomicAdd(&yrow[d], gt * acc[i][j][jj]);
        }
      }
    }
  }
}

extern "C" void kernel_launch(void* const* d_in, const int* in_sizes, int n_in,
                              void* d_out, int out_size, void* d_ws, size_t ws_size,
                              hipStream_t stream) {
  const float* x = (const float*)d_in[0];
  const float* wr = (const float*)d_in[1];
  const float* wg = (const float*)d_in[2];
  const float* wu = (const float*)d_in[3];
  const float* wd = (const float*)d_in[4];
  float* out = (float*)d_out;

  char* ws = (char*)d_ws;
  size_t off = 0;
  auto alloc = [&](size_t bytes) {
    char* p = ws + off;
    off += (bytes + 255) & ~(size_t)255;
    return p;
  };
  unsigned short* xb   = (unsigned short*)alloc((size_t)T_TOK * DIM * 2);
  unsigned short* wgb  = (unsigned short*)alloc((size_t)NE * FFN * DIM * 2);
  unsigned short* wub  = (unsigned short*)alloc((size_t)NE * FFN * DIM * 2);
  unsigned short* wdb  = (unsigned short*)alloc((size_t)NE * DIM * FFN * 2);
  unsigned short* hbuf = (unsigned short*)alloc((size_t)T_TOK * 2 * FFN * 2);
  int* top_i     = (int*)alloc(T_TOK * 2 * 4);
  float* top_g   = (float*)alloc(T_TOK * 2 * 4);
  int* tok_list  = (int*)alloc(T_TOK * 2 * 4);
  float* gate_lst = (float*)alloc(T_TOK * 2 * 4);
  int* offs      = (int*)alloc(64);
  int* cursor    = (int*)alloc(64);
  if (off > ws_size) return;

  zero_out<<<1024, 256, 0, stream>>>((float4*)out, T_TOK * DIM / 4);
  cvt_all<<<4096, 256, 0, stream>>>(x, wg, wu, wd, xb, wgb, wub, wdb);
  router_topk<<<T_TOK / 4, 256, 0, stream>>>(x, wr, top_i, top_g);
  count_offsets<<<1, 256, 0, stream>>>(top_i, offs, cursor);
  scatter_tokens<<<(T_TOK + 255) / 256, 256, 0, stream>>>(top_i, top_g, cursor, tok_list,
                                                          gate_lst);
  gateup_gemm<<<NE * 8 * 32, 256, 0, stream>>>(xb, wgb, wub, tok_list, offs, hbuf);
  down_gemm<<<NE * 16 * 32, 256, 0, stream>>>(hbuf, wdb, tok_list, gate_lst, offs, out);
}

// Round 5
// 199.796 us; speedup vs baseline: 1.6987x; 1.3108x over previous
//
#include <hip/hip_runtime.h>
#include <hip/hip_bf16.h>

// Problem dims (fixed by reference): B=2,S=1024 -> T=2048 tokens
#define T_TOK 2048
#define DIM   2048   // D
#define FFN   1024   // F
#define NE    8      // experts
// top_k = 2 hardcoded

typedef __attribute__((ext_vector_type(8))) short bf16x8;
typedef __attribute__((ext_vector_type(4))) float f32x4;

__device__ __forceinline__ unsigned short f2bf(float f) {
  __hip_bfloat16 h = __float2bfloat16(f);
  return __builtin_bit_cast(unsigned short, h);
}

__device__ __forceinline__ void gload_lds16(const unsigned short* g, unsigned short* l) {
  __builtin_amdgcn_global_load_lds(
      (const __attribute__((address_space(1))) void*)g,
      (__attribute__((address_space(3))) void*)l, 16, 0, 0);
}

// ---------------- fp32 -> bf16 conversion: x + 3 weight tensors ----------------
#define XN4 (T_TOK * DIM / 4)            // 2^20
#define WN4 (NE * FFN * DIM / 4)         // 2^22
__global__ void cvt_all(const float* __restrict__ x, const float* __restrict__ wg,
                        const float* __restrict__ wu, const float* __restrict__ wd,
                        unsigned short* __restrict__ xb, unsigned short* __restrict__ wgb,
                        unsigned short* __restrict__ wub, unsigned short* __restrict__ wdb) {
  long i = (long)blockIdx.x * blockDim.x + threadIdx.x;
  long stride = (long)gridDim.x * blockDim.x;
  const long TOTAL = (long)XN4 + 3L * WN4;
  for (; i < TOTAL; i += stride) {
    const float4* src; ushort4* dst; long j;
    if (i < XN4) {
      src = reinterpret_cast<const float4*>(x); dst = reinterpret_cast<ushort4*>(xb); j = i;
    } else {
      long k = i - XN4; int seg = (int)(k >> 22); j = k & (WN4 - 1);
      src = reinterpret_cast<const float4*>(seg == 0 ? wg : (seg == 1 ? wu : wd));
      dst = reinterpret_cast<ushort4*>(seg == 0 ? wgb : (seg == 1 ? wub : wdb));
    }
    float4 v = src[j];
    ushort4 o;
    o.x = f2bf(v.x); o.y = f2bf(v.y); o.z = f2bf(v.z); o.w = f2bf(v.w);
    dst[j] = o;
  }
}

// ---------------- router: logits + top2 + softmax gates ----------------
__global__ __launch_bounds__(256) void router_topk(
    const float* __restrict__ x, const float* __restrict__ wr,
    int* __restrict__ top_i, float* __restrict__ top_g) {
  int t = blockIdx.x * 4 + (threadIdx.x >> 6);
  int lane = threadIdx.x & 63;
  const float4* xr = reinterpret_cast<const float4*>(x) + (size_t)t * (DIM / 4);
  const float4* wrv = reinterpret_cast<const float4*>(wr);
  float acc[NE];
#pragma unroll
  for (int e = 0; e < NE; ++e) acc[e] = 0.f;
#pragma unroll
  for (int it = 0; it < DIM / 4 / 64; ++it) {
    int d4 = it * 64 + lane;
    float4 xv = xr[d4];
#pragma unroll
    for (int e = 0; e < NE; ++e) {
      float4 wv = wrv[e * (DIM / 4) + d4];
      acc[e] += xv.x * wv.x + xv.y * wv.y + xv.z * wv.z + xv.w * wv.w;
    }
  }
#pragma unroll
  for (int off = 32; off > 0; off >>= 1) {
#pragma unroll
    for (int e = 0; e < NE; ++e) acc[e] += __shfl_xor(acc[e], off, 64);
  }
  if (lane == 0) {
    int i0 = 0; float m0 = acc[0];
#pragma unroll
    for (int e = 1; e < NE; ++e) if (acc[e] > m0) { m0 = acc[e]; i0 = e; }
    int i1 = -1; float m1 = -3.4e38f;
#pragma unroll
    for (int e = 0; e < NE; ++e) if (e != i0 && acc[e] > m1) { m1 = acc[e]; i1 = e; }
    float tv = expf(m1 - m0);
    float den = 1.f + tv;
    top_i[t * 2 + 0] = i0; top_i[t * 2 + 1] = i1;
    top_g[t * 2 + 0] = 1.f / den; top_g[t * 2 + 1] = tv / den;
  }
}

// ---------------- count per expert + exclusive prefix offsets ----------------
__global__ void count_offsets(const int* __restrict__ top_i,
                              int* __restrict__ offs, int* __restrict__ cursor) {
  __shared__ int cnt[NE];
  if (threadIdx.x < NE) cnt[threadIdx.x] = 0;
  __syncthreads();
  for (int i = threadIdx.x; i < T_TOK * 2; i += blockDim.x) atomicAdd(&cnt[top_i[i]], 1);
  __syncthreads();
  if (threadIdx.x == 0) {
    int s = 0;
    for (int e = 0; e < NE; ++e) { offs[e] = s; cursor[e] = s; s += cnt[e]; }
    offs[NE] = s;
  }
}

// ---------------- scatter tokens into compact per-expert lists ----------------
__global__ void scatter_tokens(const int* __restrict__ top_i, const float* __restrict__ top_g,
                               int* __restrict__ cursor, int* __restrict__ tok_list,
                               float* __restrict__ gate_lst, int* __restrict__ slot_lst) {
  int t = blockIdx.x * blockDim.x + threadIdx.x;
  if (t >= T_TOK) return;
#pragma unroll
  for (int s = 0; s < 2; ++s) {
    int e = top_i[t * 2 + s];
    int p = atomicAdd(&cursor[e], 1);
    tok_list[p] = t;
    gate_lst[p] = top_g[t * 2 + s];
    slot_lst[p] = s;
  }
}

// ============ fused gate+up grouped GEMM: BM=64, BN=64, BK=64 ============
// R2-proven structure (stage -> sync -> compute -> sync, single buffer, swizzle),
// BN reduced 128->64: live blocks 512->1024 (4/CU) to attack the latency bound.
// LDS rows 128B = 8 x 16B chunks, swizzle c ^= (row&7).
__global__ __launch_bounds__(256, 4) void gateup_gemm(
    const unsigned short* __restrict__ xb, const unsigned short* __restrict__ wgb,
    const unsigned short* __restrict__ wub, const int* __restrict__ tok_list,
    const int* __restrict__ offs, unsigned short* __restrict__ hbuf) {
  const int e = blockIdx.z;
  const int row0 = offs[e];
  const int n_e = offs[e + 1] - row0;
  const int mt = blockIdx.y;
  if (mt * 64 >= n_e) return;
  const int nt = blockIdx.x;    // F tile of 64

  __shared__ unsigned short As[64 * 64];   // 8KB
  __shared__ unsigned short Bg[64 * 64];   // 8KB
  __shared__ unsigned short Bu[64 * 64];   // 8KB

  const int tid = threadIdx.x;
  const int wid = tid >> 6;
  const int lane = tid & 63;

  const int gchunk = (((lane & 7) ^ ((lane >> 3) & 7)) << 3);

  // A: 64 rows, per wave 16 rows in 2 passes of 8
  const unsigned short* gA[2];
  int lAoff[2];
#pragma unroll
  for (int p = 0; p < 2; ++p) {
    int rt = wid * 16 + p * 8 + (lane >> 3);
    int ar = mt * 64 + rt; if (ar >= n_e) ar = n_e - 1;
    gA[p] = xb + (size_t)tok_list[row0 + ar] * DIM + gchunk;
    lAoff[p] = (wid * 16 + p * 8) * 64;
  }
  // Bg/Bu: 64 rows each, per wave 16 rows in 2 passes of 8
  const size_t wbase = (size_t)e * FFN * DIM + (size_t)(nt * 64) * DIM;
  const unsigned short* gG[2];
  const unsigned short* gU[2];
  int lBoff[2];
#pragma unroll
  for (int p = 0; p < 2; ++p) {
    int rt = wid * 16 + p * 8 + (lane >> 3);
    gG[p] = wgb + wbase + (size_t)rt * DIM + gchunk;
    gU[p] = wub + wbase + (size_t)rt * DIM + gchunk;
    lBoff[p] = (wid * 16 + p * 8) * 64;
  }

  f32x4 accg[2][2];
  f32x4 accu[2][2];
#pragma unroll
  for (int i = 0; i < 2; ++i)
#pragma unroll
    for (int j = 0; j < 2; ++j) {
      accg[i][j] = (f32x4){0.f, 0.f, 0.f, 0.f};
      accu[i][j] = (f32x4){0.f, 0.f, 0.f, 0.f};
    }

  const int warow = (wid >> 1) * 32;   // 2x2 wave grid, 32x32 per wave
  const int wacol = (wid & 1) * 32;
  const int frow = lane & 15;
  const int eo0 = ((((lane >> 4)) ^ (lane & 7)) << 3);
  const int eo1 = (((4 + (lane >> 4)) ^ (lane & 7)) << 3);

  for (int k0 = 0; k0 < DIM; k0 += 64) {
#pragma unroll
    for (int p = 0; p < 2; ++p) {
      gload_lds16(gA[p] + k0, &As[lAoff[p]]);
      gload_lds16(gG[p] + k0, &Bg[lBoff[p]]);
      gload_lds16(gU[p] + k0, &Bu[lBoff[p]]);
    }
    __syncthreads();
#pragma unroll
    for (int kk = 0; kk < 2; ++kk) {
      const int eo = kk ? eo1 : eo0;
      bf16x8 af[2], bg[2], bu[2];
#pragma unroll
      for (int i = 0; i < 2; ++i)
        af[i] = *reinterpret_cast<const bf16x8*>(&As[(warow + i * 16 + frow) * 64 + eo]);
#pragma unroll
      for (int j = 0; j < 2; ++j) {
        bg[j] = *reinterpret_cast<const bf16x8*>(&Bg[(wacol + j * 16 + frow) * 64 + eo]);
        bu[j] = *reinterpret_cast<const bf16x8*>(&Bu[(wacol + j * 16 + frow) * 64 + eo]);
      }
#pragma unroll
      for (int i = 0; i < 2; ++i)
#pragma unroll
        for (int j = 0; j < 2; ++j) {
          accg[i][j] = __builtin_amdgcn_mfma_f32_16x16x32_bf16(af[i], bg[j], accg[i][j], 0, 0, 0);
          accu[i][j] = __builtin_amdgcn_mfma_f32_16x16x32_bf16(af[i], bu[j], accu[i][j], 0, 0, 0);
        }
    }
    __syncthreads();
  }

  // epilogue: h = silu(g)*u -> bf16
#pragma unroll
  for (int i = 0; i < 2; ++i) {
#pragma unroll
    for (int jj = 0; jj < 4; ++jj) {
      int r = mt * 64 + warow + i * 16 + (lane >> 4) * 4 + jj;
      if (r < n_e) {
#pragma unroll
        for (int j = 0; j < 2; ++j) {
          float g = accg[i][j][jj];
          float u = accu[i][j][jj];
          float h = (g / (1.f + __expf(-g))) * u;
          int f = nt * 64 + wacol + j * 16 + (lane & 15);
          hbuf[(size_t)(row0 + r) * FFN + f] = f2bf(h);
        }
      }
    }
  }
}

// ============ grouped down GEMM: BM=64, BN=128, BK=64 (R2-proven) ============
__global__ __launch_bounds__(256, 4) void down_gemm(
    const unsigned short* __restrict__ hbuf, const unsigned short* __restrict__ wdb,
    const int* __restrict__ tok_list, const float* __restrict__ gate_lst,
    const int* __restrict__ slot_lst, const int* __restrict__ offs,
    float* __restrict__ yslots) {
  const int e = blockIdx.z;
  const int row0 = offs[e];
  const int n_e = offs[e + 1] - row0;
  const int mt = blockIdx.y;
  if (mt * 64 >= n_e) return;
  const int nt = blockIdx.x;  // D tile

  __shared__ unsigned short As[64 * 64];    // 8KB
  __shared__ unsigned short Bs[128 * 64];   // 16KB

  const int tid = threadIdx.x;
  const int wid = tid >> 6;
  const int lane = tid & 63;

  const int gchunk = (((lane & 7) ^ ((lane >> 3) & 7)) << 3);

  const unsigned short* gA[2];
  int lAoff[2];
#pragma unroll
  for (int p = 0; p < 2; ++p) {
    int rt = wid * 16 + p * 8 + (lane >> 3);
    int ar = mt * 64 + rt; if (ar >= n_e) ar = n_e - 1;
    gA[p] = hbuf + (size_t)(row0 + ar) * FFN + gchunk;
    lAoff[p] = (wid * 16 + p * 8) * 64;
  }
  const unsigned short* gB[4];
  int lBoff[4];
#pragma unroll
  for (int p = 0; p < 4; ++p) {
    int rt = wid * 32 + p * 8 + (lane >> 3);
    gB[p] = wdb + ((size_t)e * DIM + nt * 128 + rt) * FFN + gchunk;
    lBoff[p] = (wid * 32 + p * 8) * 64;
  }

  f32x4 acc[2][4];
#pragma unroll
  for (int i = 0; i < 2; ++i)
#pragma unroll
    for (int j = 0; j < 4; ++j) acc[i][j] = (f32x4){0.f, 0.f, 0.f, 0.f};

  const int warow = (wid >> 1) * 32;
  const int wacol = (wid & 1) * 64;
  const int frow = lane & 15;
  const int eo0 = ((((lane >> 4)) ^ (lane & 7)) << 3);
  const int eo1 = (((4 + (lane >> 4)) ^ (lane & 7)) << 3);

  for (int k0 = 0; k0 < FFN; k0 += 64) {
#pragma unroll
    for (int p = 0; p < 2; ++p) gload_lds16(gA[p] + k0, &As[lAoff[p]]);
#pragma unroll
    for (int p = 0; p < 4; ++p) gload_lds16(gB[p] + k0, &Bs[lBoff[p]]);
    __syncthreads();
#pragma unroll
    for (int kk = 0; kk < 2; ++kk) {
      const int eo = kk ? eo1 : eo0;
      bf16x8 af[2], bf[4];
#pragma unroll
      for (int i = 0; i < 2; ++i)
        af[i] = *reinterpret_cast<const bf16x8*>(&As[(warow + i * 16 + frow) * 64 + eo]);
#pragma unroll
      for (int j = 0; j < 4; ++j)
        bf[j] = *reinterpret_cast<const bf16x8*>(&Bs[(wacol + j * 16 + frow) * 64 + eo]);
#pragma unroll
      for (int i = 0; i < 2; ++i)
#pragma unroll
        for (int j = 0; j < 4; ++j)
          acc[i][j] = __builtin_amdgcn_mfma_f32_16x16x32_bf16(af[i], bf[j], acc[i][j], 0, 0, 0);
    }
    __syncthreads();
  }

#pragma unroll
  for (int i = 0; i < 2; ++i) {
#pragma unroll
    for (int jj = 0; jj < 4; ++jj) {
      int r = mt * 64 + warow + i * 16 + (lane >> 4) * 4 + jj;
      if (r < n_e) {
        int tk = tok_list[row0 + r];
        float gt = gate_lst[row0 + r];
        int sl = slot_lst[row0 + r];
        float* yrow = yslots + ((size_t)sl * T_TOK + tk) * DIM;
#pragma unroll
        for (int j = 0; j < 4; ++j) {
          int d = nt * 128 + wacol + j * 16 + (lane & 15);
          yrow[d] = gt * acc[i][j][jj];
        }
      }
    }
  }
}

// ---------------- combine slots ----------------
__global__ void combine(const float* __restrict__ y, float* __restrict__ out) {
  int i = blockIdx.x * blockDim.x + threadIdx.x;
  int stride = gridDim.x * blockDim.x;
  const float4* y0 = reinterpret_cast<const float4*>(y);
  const float4* y1 = reinterpret_cast<const float4*>(y + (size_t)T_TOK * DIM);
  float4* o = reinterpret_cast<float4*>(out);
  for (; i < T_TOK * DIM / 4; i += stride) {
    float4 a = y0[i], b = y1[i];
    float4 r;
    r.x = a.x + b.x; r.y = a.y + b.y; r.z = a.z + b.z; r.w = a.w + b.w;
    o[i] = r;
  }
}

extern "C" void kernel_launch(void* const* d_in, const int* in_sizes, int n_in,
                              void* d_out, int out_size, void* d_ws, size_t ws_size,
                              hipStream_t stream) {
  const float* x = (const float*)d_in[0];
  const float* wr = (const float*)d_in[1];
  const float* wg = (const float*)d_in[2];
  const float* wu = (const float*)d_in[3];
  const float* wd = (const float*)d_in[4];
  float* out = (float*)d_out;

  char* ws = (char*)d_ws;
  size_t off = 0;
  auto alloc = [&](size_t bytes) {
    char* p = ws + off;
    off += (bytes + 255) & ~(size_t)255;
    return p;
  };
  unsigned short* xb   = (unsigned short*)alloc((size_t)T_TOK * DIM * 2);
  unsigned short* wgb  = (unsigned short*)alloc((size_t)NE * FFN * DIM * 2);
  unsigned short* wub  = (unsigned short*)alloc((size_t)NE * FFN * DIM * 2);
  unsigned short* wdb  = (unsigned short*)alloc((size_t)NE * DIM * FFN * 2);
  unsigned short* hbuf = (unsigned short*)alloc((size_t)T_TOK * 2 * FFN * 2);
  float* yslots        = (float*)alloc((size_t)2 * T_TOK * DIM * 4);
  int* top_i     = (int*)alloc(T_TOK * 2 * 4);
  float* top_g   = (float*)alloc(T_TOK * 2 * 4);
  int* tok_list  = (int*)alloc(T_TOK * 2 * 4);
  float* gate_lst = (float*)alloc(T_TOK * 2 * 4);
  int* slot_lst  = (int*)alloc(T_TOK * 2 * 4);
  int* offs      = (int*)alloc(64);
  int* cursor    = (int*)alloc(64);
  if (off > ws_size) return;

  cvt_all<<<4096, 256, 0, stream>>>(x, wg, wu, wd, xb, wgb, wub, wdb);
  router_topk<<<T_TOK / 4, 256, 0, stream>>>(x, wr, top_i, top_g);
  count_offsets<<<1, 256, 0, stream>>>(top_i, offs, cursor);
  scatter_tokens<<<(T_TOK + 255) / 256, 256, 0, stream>>>(top_i, top_g, cursor, tok_list,
                                                          gate_lst, slot_lst);
  // BN=64: live blocks ~1024 (4/CU) to attack the latency bound
  gateup_gemm<<<dim3(FFN / 64, 32, NE), 256, 0, stream>>>(xb, wgb, wub, tok_list, offs, hbuf);
  down_gemm<<<dim3(DIM / 128, 32, NE), 256, 0, stream>>>(hbuf, wdb, tok_list, gate_lst,
                                                         slot_lst, offs, yslots);
  combine<<<2048, 256, 0, stream>>>(yslots, out);
}